// Round 23
// baseline (2887.963 us; speedup 1.0000x reference)
//
#include <hip/hip_runtime.h>

// Numerics frozen from R20 (PASSED, absmax 0.0039):
//  conv1: (kh,kw,ic) flat FMA chain; conv2: (kh,kw,ic) with 4 panel chains
//  split at k=152/304/456 (tap2:ic24, tap4:ic48, tap7:ic8), joined
//  ((P0+P1)+P2)+P3 then bias; LIF f32 two-rounding v+0.5*(x-v); head:
//  ascending-oc conditional-add chain per c. All changes structure-only.
// R23: conv2 layout B — lane = pixel, oc serial. Per term:
//  v_bfe_i32 (mask VGPR, -bit) + v_and (weight via SGPR src0) + v_add
//  = 3 VALU, 0 SALU. Weights transposed to [oc][tap][ic] for s_load batching.
//  Spikes stored as bytes [b][t][oc][px]; head reads bytes, same chain.

#define NB    8
#define HW    128
#define NPIX  (HW*HW)          // 16384
#define NT    5

__device__ __forceinline__ unsigned negbit(unsigned m, int off) {
#if defined(__has_builtin) && __has_builtin(__builtin_amdgcn_sbfe)
    return (unsigned)__builtin_amdgcn_sbfe((int)m, off, 1);   // v_bfe_i32: -(bit)
#else
    return (unsigned)((int)(m << (31 - off)) >> 31);
#endif
}

// ---------------- W2 [oc][ic][tap] -> Wt2 [oc][tap][ic]  (contiguous chain order)
__global__ void k_transpose_w2(const float* __restrict__ W2, float* __restrict__ Wt2) {
    int i = blockIdx.x * 256 + threadIdx.x;      // 36864
    if (i >= 64 * 9 * 64) return;
    int ic = i & 63;
    int tap = (i >> 6) % 9;
    int oc = i / (9 * 64);
    Wt2[i] = W2[(oc * 64 + ic) * 9 + tap];
}

// ---------------- conv1 ((kh,kw,ic) flat FMA) + LIF1 -> ballot-packed masks
__global__ __launch_bounds__(256) void k_conv1_lif1(
    const float* __restrict__ lab, const float* __restrict__ W1,
    const float* __restrict__ b1, const float* __restrict__ tau1,
    unsigned long long* __restrict__ smask)
{
#pragma clang fp contract(off)
    __shared__ float w1s[64 * 27];
    __shared__ float b1s[64];
    {
        int tid = threadIdx.x;
        for (int e = tid; e < 64 * 27; e += 256) w1s[e] = W1[e];
        if (tid < 64) b1s[tid] = b1[tid];
        __syncthreads();
    }
    int g = blockIdx.x * 256 + threadIdx.x;      // (b,y,x,oc) — lane = oc
    int oc = g & 63;
    int x = (g >> 6) & (HW - 1);
    int y = (g >> 13) & (HW - 1);
    int b = g >> 20;

    const float* wbase = w1s + oc * 27;
    const float* ibase = lab + b * 3 * NPIX;
    float acc = 0.f;
    for (int kh = 0; kh < 3; ++kh) {             // identical chain to R20
        int yy = y + kh - 1;
        if ((unsigned)yy >= (unsigned)HW) continue;
        for (int kw = 0; kw < 3; ++kw) {
            int xx = x + kw - 1;
            if ((unsigned)xx >= (unsigned)HW) continue;
            const float* px = ibase + yy * HW + xx;
#pragma unroll
            for (int ic = 0; ic < 3; ++ic) {
                acc = __builtin_fmaf(wbase[ic * 9 + kh * 3 + kw], px[ic * NPIX], acc);
            }
        }
    }
    float xin = acc + b1s[oc];

    float tauc = fminf(fmaxf(tau1[0], 0.5f), 5.0f);
    float it = 1.0f / tauc;

    float v = 0.f;
    unsigned bits = 0;
    for (int t = 0; t < NT; ++t) {
        float d = xin - v;
        float m = it * d;
        v = v + m;
        bool s = (v - 0.1f) >= 0.f;
        float vr = s ? 0.f : v;
        vr = fmaxf(vr, -2.f);
        vr = fminf(vr, 2.f);
        v = vr;
        if (s) bits |= (1u << t);
    }
    for (int t = 0; t < NT; ++t) {
        unsigned long long bal = __ballot((bits >> t) & 1);
        if (oc == 0) smask[((size_t)(b * NT + t) * NPIX) + y * HW + x] = bal;
    }
}

// ---------------- conv2 (lane = pixel) + LIF2 -> byte spikes [b][t][oc][px]
// SEGB: ic range of one tap into panel accumulator PN. wq = Wt2 + oc*576 (uint).
#define SEGB(TAP, IC0, IC1, PN)                                         \
    _Pragma("unroll")                                                   \
    for (int ic = IC0; ic < IC1; ++ic) {                                \
        unsigned nb = negbit((ic < 32) ? mlo : mhi, ic & 31);           \
        unsigned sel = wq[TAP * 64 + ic] & nb;                          \
        a##PN = a##PN + __uint_as_float(sel);                           \
    }

#define TAPB(KH, KW, SEGS) {                                            \
    const int yy = y + KH - 1;                                          \
    const int xx = x + KW - 1;                                          \
    unsigned long long mm = 0ULL;                                       \
    if (((unsigned)yy < (unsigned)HW) && ((unsigned)xx < (unsigned)HW)) \
        mm = smb[yy * HW + xx];                                         \
    const unsigned mlo = (unsigned)mm, mhi = (unsigned)(mm >> 32);      \
    SEGS }

__global__ __launch_bounds__(256) void k_conv2_lif2(
    const unsigned long long* __restrict__ smask,
    const float* __restrict__ Wt2, const float* __restrict__ b2,
    const float* __restrict__ tau2, unsigned char* __restrict__ s2b)
{
#pragma clang fp contract(off)
    const int tid = threadIdx.x;
    const int lane = tid & 63;
    const int wv = __builtin_amdgcn_readfirstlane(tid >> 6);  // oc-group 0..3
    const int pos = blockIdx.x;                  // (b, y, xseg): 8*128*2 = 2048
    const int b = pos >> 8;
    const int rem = pos & 255;
    const int y = rem >> 1;
    const int x = (rem & 1) * 64 + lane;         // lane = pixel x

    float tauc = fminf(fmaxf(tau2[0], 0.5f), 5.0f);
    const float it = 1.0f / tauc;

    for (int ocl = 0; ocl < 16; ++ocl) {
        const int oc = wv * 16 + ocl;
        const unsigned* wq = (const unsigned*)(Wt2 + oc * 576);  // [tap][ic]
        const float b2oc = b2[oc];
        float v = 0.f;
        for (int t = 0; t < NT; ++t) {
            const unsigned long long* smb = smask + (size_t)(b * NT + t) * NPIX;
            float a0 = 0.f, a1 = 0.f, a2 = 0.f, a3 = 0.f;
            // taps (kh,kw) ascending; ic ascending; panels split 152/304/456
            TAPB(0, 0, SEGB(0, 0, 64, 0))
            TAPB(0, 1, SEGB(1, 0, 64, 0))
            TAPB(0, 2, SEGB(2, 0, 24, 0) SEGB(2, 24, 64, 1))
            TAPB(1, 0, SEGB(3, 0, 64, 1))
            TAPB(1, 1, SEGB(4, 0, 48, 1) SEGB(4, 48, 64, 2))
            TAPB(1, 2, SEGB(5, 0, 64, 2))
            TAPB(2, 0, SEGB(6, 0, 64, 2))
            TAPB(2, 1, SEGB(7, 0, 8, 2) SEGB(7, 8, 64, 3))
            TAPB(2, 2, SEGB(8, 0, 64, 3))

            float x2 = (((a0 + a1) + a2) + a3) + b2oc;
            float d = x2 - v;                    // t=0: v==0 — frozen LIF chain
            float m = it * d;
            float vp = v + m;
            bool s = (vp - 0.1f) >= 0.f;
            float vr = s ? 0.f : vp;
            vr = fmaxf(vr, -2.f);
            vr = fminf(vr, 2.f);
            v = vr;
            s2b[((size_t)(b * NT + t) * 64 + oc) * NPIX + y * HW + x] = (unsigned char)s;
        }
    }
}

// ---------------- head 1x1 from byte spikes
__global__ __launch_bounds__(256) void k_head(
    const unsigned char* __restrict__ s2b, const float* __restrict__ Wh,
    const float* __restrict__ bh, float* __restrict__ out)
{
#pragma clang fp contract(off)
    __shared__ float whs[192];
    __shared__ float bhs[3];
    {
        int tid = threadIdx.x;
        if (tid < 192) whs[tid] = Wh[tid];
        if (tid < 3) bhs[tid] = bh[tid];
        __syncthreads();
    }
    int g = blockIdx.x * 256 + threadIdx.x;      // (t,b,px): 5*8*16384
    int px = g & (NPIX - 1);
    int r = g >> 14;
    int b = r & 7;
    int t = r >> 3;

    const unsigned char* sp = s2b + ((size_t)(b * NT + t) * 64) * NPIX + px;
    float c0 = 0.f, c1 = 0.f, c2 = 0.f;
    for (int oc = 0; oc < 64; ++oc) {            // ascending oc — frozen chain
        if (sp[oc * NPIX]) {
            c0 = c0 + whs[oc];
            c1 = c1 + whs[64 + oc];
            c2 = c2 + whs[128 + oc];
        }
    }
    int obase = ((t * NB + b) * 3) * NPIX + px;
    out[obase] = c0 + bhs[0];
    out[obase + NPIX] = c1 + bhs[1];
    out[obase + 2 * NPIX] = c2 + bhs[2];
}

extern "C" void kernel_launch(void* const* d_in, const int* in_sizes, int n_in,
                              void* d_out, int out_size, void* d_ws, size_t ws_size,
                              hipStream_t stream) {
    const float* lab  = (const float*)d_in[0];
    const float* W1   = (const float*)d_in[1];
    const float* b1   = (const float*)d_in[2];
    const float* tau1 = (const float*)d_in[3];
    const float* W2   = (const float*)d_in[4];
    const float* b2   = (const float*)d_in[5];
    const float* tau2 = (const float*)d_in[6];
    const float* Wh   = (const float*)d_in[7];
    const float* bh   = (const float*)d_in[8];
    float* out = (float*)d_out;

    // ws: smask 5.25MB | s2b 41.9MB | Wt2 147KB
    const size_t SZ_SM = (size_t)NB * NT * NPIX * 8;         //  5,242,880
    const size_t SZ_S2 = (size_t)NB * NT * 64 * NPIX;        // 41,943,040
    const size_t SZ_WT = 64 * 9 * 64 * 4;                    //    147,456
    if (ws_size < SZ_SM + SZ_S2 + SZ_WT) return;

    char* ws = (char*)d_ws;
    unsigned long long* smask = (unsigned long long*)ws;
    unsigned char* s2b        = (unsigned char*)(ws + SZ_SM);
    float* Wt2                = (float*)(ws + SZ_SM + SZ_S2);

    hipLaunchKernelGGL(k_transpose_w2, dim3(144), dim3(256), 0, stream, W2, Wt2);
    hipLaunchKernelGGL(k_conv1_lif1, dim3(NB * 64 * NPIX / 256), dim3(256), 0, stream,
                       lab, W1, b1, tau1, smask);
    hipLaunchKernelGGL(k_conv2_lif2, dim3(2048), dim3(256), 0, stream,
                       smask, Wt2, b2, tau2, s2b);
    hipLaunchKernelGGL(k_head, dim3(NT * NB * NPIX / 256), dim3(256), 0, stream,
                       s2b, Wh, bh, out);
}